// Round 2
// baseline (286.803 us; speedup 1.0000x reference)
//
#include <hip/hip_runtime.h>
#include <cstdint>
#include <cstddef>

#define WS 64
#define SHIFT 32
#define WTOT 8192
#define NWIN 128
#define SCALE_F 0.125f
#define LDS_STRIDE 72   // 64 + 8 elem pad: 144 B rows, 16B-aligned, breaks bank alignment

typedef __bf16 bf16x8 __attribute__((ext_vector_type(8)));
typedef unsigned short u16x8 __attribute__((ext_vector_type(8)));
typedef float f32x4 __attribute__((ext_vector_type(4)));

// Truncation split: hi = trunc_bf16(f), lo = trunc_bf16(f - hi).
// f - hi is exact (same-exponent subtraction), so total error ~2^-16 relative.
__device__ __forceinline__ void split1(float f, unsigned short& h, unsigned short& l) {
  const unsigned u = __builtin_bit_cast(unsigned, f);
  h = (unsigned short)(u >> 16);
  const float hf = __builtin_bit_cast(float, u & 0xFFFF0000u);
  const float r = f - hf;
  l = (unsigned short)(__builtin_bit_cast(unsigned, r) >> 16);
}

__device__ __forceinline__ void split8(const float* f, bf16x8& hi, bf16x8& lo) {
  u16x8 hv, lv;
#pragma unroll
  for (int e = 0; e < 8; ++e) {
    unsigned short hh, ll;
    split1(f[e], hh, ll);
    hv[e] = hh; lv[e] = ll;
  }
  hi = __builtin_bit_cast(bf16x8, hv);
  lo = __builtin_bit_cast(bf16x8, lv);
}

// One block (256 thr = 4 waves) per 64x64 window. 4096 blocks.
__global__ __launch_bounds__(256, 4) void win_attn(
    const float* __restrict__ q, const float* __restrict__ k,
    const float* __restrict__ v, const float* __restrict__ table,
    float* __restrict__ xout, float* __restrict__ attn_out) {
  // K hi/lo (reused for P hi/lo after QK^T), V^T hi/lo. Q never hits LDS.
  __shared__ __align__(16) unsigned short s_k[2][WS * LDS_STRIDE];
  __shared__ __align__(16) unsigned short s_vt[2][WS * LDS_STRIDE];
  __shared__ float s_bias[2 * WS - 1];

  const int t = threadIdx.x;
  const int b = blockIdx.x;
  const int batch = b >> 7;
  const int win = b & (NWIN - 1);

  const int lane = t & 63;
  const int wave = t >> 6;
  const int lrow = lane & 15;
  const int quad = lane >> 4;

  if (t < 2 * WS - 1) s_bias[t] = table[t];

  // ---------- Q A-fragments straight from global into registers ----------
  bf16x8 aq_hi[2], aq_lo[2];
  {
    const int qrow = wave * 16 + lrow;
    const int gq = (win * WS + qrow + SHIFT) & (WTOT - 1);
    const float* qp = q + ((size_t)batch * WTOT + gq) * WS;
#pragma unroll
    for (int kh = 0; kh < 2; ++kh) {
      const float4 f0 = *(const float4*)(qp + kh * 32 + quad * 8);
      const float4 f1 = *(const float4*)(qp + kh * 32 + quad * 8 + 4);
      const float fa[8] = {f0.x, f0.y, f0.z, f0.w, f1.x, f1.y, f1.z, f1.w};
      split8(fa, aq_hi[kh], aq_lo[kh]);
    }
  }

  // ---------- K -> LDS (packed b128 hi/lo), V -> LDS transposed ----------
  {
    const int lr = t >> 2;                      // row 0..63
    const int gk = (win * WS + lr + SHIFT) & (WTOT - 1);
    const size_t gbase = ((size_t)batch * WTOT + gk) * WS;

    // K: 16 contiguous cols per thread, 2 packed b128 writes per buffer
    const int lck = (t & 3) << 4;
    const float* kp = k + gbase + lck;
#pragma unroll
    for (int g = 0; g < 2; ++g) {
      const float4 f0 = *(const float4*)(kp + g * 8);
      const float4 f1 = *(const float4*)(kp + g * 8 + 4);
      const float fa[8] = {f0.x, f0.y, f0.z, f0.w, f1.x, f1.y, f1.z, f1.w};
      bf16x8 hi, lo;
      split8(fa, hi, lo);
      *(bf16x8*)(&s_k[0][lr * LDS_STRIDE + lck + g * 8]) = hi;
      *(bf16x8*)(&s_k[1][lr * LDS_STRIDE + lck + g * 8]) = lo;
    }

    // V: 4-col groups (bank-spread scatter), transposed store
    const int cv = (t & 3) << 2;
#pragma unroll
    for (int blk = 0; blk < 4; ++blk) {
      const float4 vv = *(const float4*)(v + gbase + cv + blk * 16);
      const float va[4] = {vv.x, vv.y, vv.z, vv.w};
#pragma unroll
      for (int e = 0; e < 4; ++e) {
        const int cc = cv + blk * 16 + e;
        unsigned short h, l;
        split1(va[e], h, l);
        s_vt[0][cc * LDS_STRIDE + lr] = h;
        s_vt[1][cc * LDS_STRIDE + lr] = l;
      }
    }
  }
  __syncthreads();

  // ---------- S = Q K^T (split-bf16, 3 MFMA per tile) ----------
  const f32x4 z4 = {0.f, 0.f, 0.f, 0.f};
  f32x4 acc[4] = {z4, z4, z4, z4};
#pragma unroll
  for (int kh = 0; kh < 2; ++kh) {
    const bf16x8 ahi = aq_hi[kh];
    const bf16x8 alo = aq_lo[kh];
    const int k0 = kh * 32 + quad * 8;
#pragma unroll
    for (int j = 0; j < 4; ++j) {
      const bf16x8 bhi = *(const bf16x8*)(&s_k[0][(j * 16 + lrow) * LDS_STRIDE + k0]);
      const bf16x8 blo = *(const bf16x8*)(&s_k[1][(j * 16 + lrow) * LDS_STRIDE + k0]);
      acc[j] = __builtin_amdgcn_mfma_f32_16x16x32_bf16(ahi, bhi, acc[j], 0, 0, 0);
      acc[j] = __builtin_amdgcn_mfma_f32_16x16x32_bf16(alo, bhi, acc[j], 0, 0, 0);
      acc[j] = __builtin_amdgcn_mfma_f32_16x16x32_bf16(ahi, blo, acc[j], 0, 0, 0);
    }
  }

  // ---------- softmax in registers (row = 16 lanes of one quad) ----------
  const bool masked = (win == NWIN - 1);
  float p[4][4];
#pragma unroll
  for (int reg = 0; reg < 4; ++reg) {
    const int r = wave * 16 + quad * 4 + reg;
    float val[4];
    float vmax = -1e30f;
#pragma unroll
    for (int j = 0; j < 4; ++j) {
      const int m = j * 16 + lrow;
      float s = acc[j][reg] * SCALE_F + s_bias[r - m + (WS - 1)];
      if (masked && (((r ^ m) & 32) != 0)) s -= 100.0f;
      val[j] = s;
      vmax = fmaxf(vmax, s);
    }
#pragma unroll
    for (int off = 1; off < 16; off <<= 1)
      vmax = fmaxf(vmax, __shfl_xor(vmax, off, 64));
    float sum = 0.f;
#pragma unroll
    for (int j = 0; j < 4; ++j) {
      val[j] = __expf(val[j] - vmax);
      sum += val[j];
    }
#pragma unroll
    for (int off = 1; off < 16; off <<= 1)
      sum += __shfl_xor(sum, off, 64);
    const float inv = 1.0f / sum;
#pragma unroll
    for (int j = 0; j < 4; ++j) p[reg][j] = val[j] * inv;
  }

  // ---------- attn out (nontemporal scalar; 4x64B segments per instr) ----------
  {
    float* arow = attn_out + (size_t)b * (WS * WS);
#pragma unroll
    for (int reg = 0; reg < 4; ++reg) {
      const int r = wave * 16 + quad * 4 + reg;
#pragma unroll
      for (int j = 0; j < 4; ++j) {
        const int m = j * 16 + lrow;
        __builtin_nontemporal_store(p[reg][j], arow + r * WS + m);
      }
    }
  }

  // all waves must finish K-fragment reads before P overwrites the K region
  __syncthreads();

  // ---------- stage P hi/lo into (dead) K region ----------
  // wave w writes rows [16w,16w+16) and later reads only those rows -> no
  // further barrier needed (per-wave DS ordering).
#pragma unroll
  for (int reg = 0; reg < 4; ++reg) {
    const int r = wave * 16 + quad * 4 + reg;
#pragma unroll
    for (int j = 0; j < 4; ++j) {
      const int m = j * 16 + lrow;
      unsigned short h, l;
      split1(p[reg][j], h, l);
      s_k[0][r * LDS_STRIDE + m] = h;
      s_k[1][r * LDS_STRIDE + m] = l;
    }
  }

  // ---------- X = P V (split-bf16) ----------
  f32x4 xacc[4] = {z4, z4, z4, z4};
#pragma unroll
  for (int kh = 0; kh < 2; ++kh) {
    const int k0 = kh * 32 + quad * 8;
    const bf16x8 phi = *(const bf16x8*)(&s_k[0][(wave * 16 + lrow) * LDS_STRIDE + k0]);
    const bf16x8 plo = *(const bf16x8*)(&s_k[1][(wave * 16 + lrow) * LDS_STRIDE + k0]);
#pragma unroll
    for (int j = 0; j < 4; ++j) {
      const bf16x8 vhi = *(const bf16x8*)(&s_vt[0][(j * 16 + lrow) * LDS_STRIDE + k0]);
      const bf16x8 vlo = *(const bf16x8*)(&s_vt[1][(j * 16 + lrow) * LDS_STRIDE + k0]);
      xacc[j] = __builtin_amdgcn_mfma_f32_16x16x32_bf16(phi, vhi, xacc[j], 0, 0, 0);
      xacc[j] = __builtin_amdgcn_mfma_f32_16x16x32_bf16(plo, vhi, xacc[j], 0, 0, 0);
      xacc[j] = __builtin_amdgcn_mfma_f32_16x16x32_bf16(phi, vlo, xacc[j], 0, 0, 0);
    }
  }

  // ---------- store x with reverse cyclic shift ----------
#pragma unroll
  for (int reg = 0; reg < 4; ++reg) {
    const int r = wave * 16 + quad * 4 + reg;
    const int gr = (win * WS + r + SHIFT) & (WTOT - 1);
    float* xrow = xout + ((size_t)batch * WTOT + gr) * WS;
#pragma unroll
    for (int j = 0; j < 4; ++j) {
      __builtin_nontemporal_store(xacc[j][reg], xrow + j * 16 + lrow);
    }
  }
}

extern "C" void kernel_launch(void* const* d_in, const int* in_sizes, int n_in,
                              void* d_out, int out_size, void* d_ws, size_t ws_size,
                              hipStream_t stream) {
  (void)in_sizes; (void)n_in; (void)out_size; (void)d_ws; (void)ws_size;
  const float* q = (const float*)d_in[0];
  const float* k = (const float*)d_in[1];
  const float* v = (const float*)d_in[2];
  const float* table = (const float*)d_in[3];
  float* xout = (float*)d_out;                               // (32, 8192, 64)
  float* attn = (float*)d_out + (size_t)32 * WTOT * WS;      // (4096, 64, 64)
  win_attn<<<dim3(4096), dim3(256), 0, stream>>>(q, k, v, table, xout, attn);
}

// Round 3
// 284.402 us; speedup vs baseline: 1.0084x; 1.0084x over previous
//
#include <hip/hip_runtime.h>
#include <cstdint>
#include <cstddef>

#define WS 64
#define SHIFT 32
#define WTOT 8192
#define NWIN 128
#define SCALE_F 0.125f
#define LSTR 72   // padded LDS row stride (elems): 144 B, 16B-aligned

typedef __bf16 bf16x8 __attribute__((ext_vector_type(8)));
typedef unsigned short u16x8 __attribute__((ext_vector_type(8)));
typedef float f32x4 __attribute__((ext_vector_type(4)));

// Truncation split for Q/K (hi+lo used, combined error ~2^-16 relative).
__device__ __forceinline__ void split1(float f, unsigned short& h, unsigned short& l) {
  const unsigned u = __builtin_bit_cast(unsigned, f);
  h = (unsigned short)(u >> 16);
  const float hf = __builtin_bit_cast(float, u & 0xFFFF0000u);
  const float r = f - hf;
  l = (unsigned short)(__builtin_bit_cast(unsigned, r) >> 16);
}

__device__ __forceinline__ void split8(const float* f, bf16x8& hi, bf16x8& lo) {
  u16x8 hv, lv;
#pragma unroll
  for (int e = 0; e < 8; ++e) {
    unsigned short hh, ll;
    split1(f[e], hh, ll);
    hv[e] = hh; lv[e] = ll;
  }
  hi = __builtin_bit_cast(bf16x8, hv);
  lo = __builtin_bit_cast(bf16x8, lv);
}

// RNE bf16 for V and P (single-precision path, error enters linearly).
__device__ __forceinline__ unsigned short rne1(float f) {
  unsigned u = __builtin_bit_cast(unsigned, f);
  u += 0x7FFFu + ((u >> 16) & 1u);
  return (unsigned short)(u >> 16);
}

// One block (256 thr = 4 waves) per 64x64 window. 4096 blocks.
__global__ __launch_bounds__(256, 5) void win_attn(
    const float* __restrict__ q, const float* __restrict__ k,
    const float* __restrict__ v, const float* __restrict__ table,
    float* __restrict__ xout, float* __restrict__ attn_out) {
  __shared__ __align__(16) unsigned short s_k[2][WS * LSTR];  // K hi/lo; [0] reused for P
  __shared__ __align__(16) unsigned short s_vt[WS * LSTR];    // V^T (RNE bf16)
  __shared__ float s_bias[2 * WS - 1];

  const int t = threadIdx.x;
  const int b = blockIdx.x;
  const int batch = b >> 7;
  const int win = b & (NWIN - 1);

  const int lane = t & 63;
  const int wave = t >> 6;
  const int lrow = lane & 15;
  const int quad = lane >> 4;

  // ---------- addresses ----------
  const int qrow = wave * 16 + lrow;
  const int gq = (win * WS + qrow + SHIFT) & (WTOT - 1);
  const float* qp = q + ((size_t)batch * WTOT + gq) * WS;

  const int lr = t >> 2;                      // staging row 0..63
  const int gk = (win * WS + lr + SHIFT) & (WTOT - 1);
  const size_t gbase = ((size_t)batch * WTOT + gk) * WS;
  const int lck = (t & 3) << 4;               // K cols: 16 contiguous
  const float* kp = k + gbase + lck;
  const int cv = (t & 3) << 2;                // V col group base
  const float* vp = v + gbase;

  // ---------- issue ALL global loads before any conversion (max MLP) ----------
  float4 L[12];
  L[0] = *(const float4*)(qp + quad * 8);
  L[1] = *(const float4*)(qp + quad * 8 + 4);
  L[2] = *(const float4*)(qp + 32 + quad * 8);
  L[3] = *(const float4*)(qp + 32 + quad * 8 + 4);
  L[4] = *(const float4*)(kp + 0);
  L[5] = *(const float4*)(kp + 4);
  L[6] = *(const float4*)(kp + 8);
  L[7] = *(const float4*)(kp + 12);
  L[8]  = *(const float4*)(vp + cv);
  L[9]  = *(const float4*)(vp + cv + 16);
  L[10] = *(const float4*)(vp + cv + 32);
  L[11] = *(const float4*)(vp + cv + 48);

  if (t < 2 * WS - 1) s_bias[t] = table[t];

  // ---------- K -> LDS hi/lo (packed b128) ----------
#pragma unroll
  for (int g = 0; g < 2; ++g) {
    const float4 f0 = L[4 + 2 * g];
    const float4 f1 = L[5 + 2 * g];
    const float fa[8] = {f0.x, f0.y, f0.z, f0.w, f1.x, f1.y, f1.z, f1.w};
    bf16x8 hi, lo;
    split8(fa, hi, lo);
    *(bf16x8*)(&s_k[0][lr * LSTR + lck + g * 8]) = hi;
    *(bf16x8*)(&s_k[1][lr * LSTR + lck + g * 8]) = lo;
  }

  // ---------- V -> LDS transposed (RNE bf16) ----------
#pragma unroll
  for (int blk = 0; blk < 4; ++blk) {
    const float4 vv = L[8 + blk];
    const float va[4] = {vv.x, vv.y, vv.z, vv.w};
#pragma unroll
    for (int e = 0; e < 4; ++e) {
      const int cc = cv + blk * 16 + e;
      s_vt[cc * LSTR + lr] = rne1(va[e]);
    }
  }

  // ---------- Q A-fragments in registers (hi/lo split) ----------
  bf16x8 aq_hi[2], aq_lo[2];
#pragma unroll
  for (int kh = 0; kh < 2; ++kh) {
    const float4 f0 = L[2 * kh];
    const float4 f1 = L[2 * kh + 1];
    const float fa[8] = {f0.x, f0.y, f0.z, f0.w, f1.x, f1.y, f1.z, f1.w};
    split8(fa, aq_hi[kh], aq_lo[kh]);
  }
  __syncthreads();

  // ---------- S = Q K^T (split-bf16, 3 MFMA per tile) ----------
  const f32x4 z4 = {0.f, 0.f, 0.f, 0.f};
  f32x4 acc[4] = {z4, z4, z4, z4};
#pragma unroll
  for (int kh = 0; kh < 2; ++kh) {
    const bf16x8 ahi = aq_hi[kh];
    const bf16x8 alo = aq_lo[kh];
    const int k0 = kh * 32 + quad * 8;
#pragma unroll
    for (int j = 0; j < 4; ++j) {
      const bf16x8 bhi = *(const bf16x8*)(&s_k[0][(j * 16 + lrow) * LSTR + k0]);
      const bf16x8 blo = *(const bf16x8*)(&s_k[1][(j * 16 + lrow) * LSTR + k0]);
      acc[j] = __builtin_amdgcn_mfma_f32_16x16x32_bf16(ahi, bhi, acc[j], 0, 0, 0);
      acc[j] = __builtin_amdgcn_mfma_f32_16x16x32_bf16(alo, bhi, acc[j], 0, 0, 0);
      acc[j] = __builtin_amdgcn_mfma_f32_16x16x32_bf16(ahi, blo, acc[j], 0, 0, 0);
    }
  }

  // ---------- softmax in registers (row = 16 lanes of one quad) ----------
  const bool masked = (win == NWIN - 1);
  float p[4][4];
#pragma unroll
  for (int reg = 0; reg < 4; ++reg) {
    const int r = wave * 16 + quad * 4 + reg;
    float val[4];
    float vmax = -1e30f;
#pragma unroll
    for (int j = 0; j < 4; ++j) {
      const int m = j * 16 + lrow;
      float s = acc[j][reg] * SCALE_F + s_bias[r - m + (WS - 1)];
      if (masked && (((r ^ m) & 32) != 0)) s -= 100.0f;
      val[j] = s;
      vmax = fmaxf(vmax, s);
    }
#pragma unroll
    for (int off = 1; off < 16; off <<= 1)
      vmax = fmaxf(vmax, __shfl_xor(vmax, off, 64));
    float sum = 0.f;
#pragma unroll
    for (int j = 0; j < 4; ++j) {
      val[j] = __expf(val[j] - vmax);
      sum += val[j];
    }
#pragma unroll
    for (int off = 1; off < 16; off <<= 1)
      sum += __shfl_xor(sum, off, 64);
    const float inv = 1.0f / sum;
#pragma unroll
    for (int j = 0; j < 4; ++j) p[reg][j] = val[j] * inv;
  }

  // ---------- attn out (fp32 exact) ----------
  {
    float* arow = attn_out + (size_t)b * (WS * WS);
#pragma unroll
    for (int reg = 0; reg < 4; ++reg) {
      const int r = wave * 16 + quad * 4 + reg;
#pragma unroll
      for (int j = 0; j < 4; ++j) {
        __builtin_nontemporal_store(p[reg][j], arow + r * WS + j * 16 + lrow);
      }
    }
  }

  // all waves must finish K-fragment reads before P overwrites the K region
  __syncthreads();

  // ---------- stage P (RNE bf16) into dead K-hi region ----------
#pragma unroll
  for (int reg = 0; reg < 4; ++reg) {
    const int r = wave * 16 + quad * 4 + reg;
#pragma unroll
    for (int j = 0; j < 4; ++j) {
      s_k[0][r * LSTR + j * 16 + lrow] = rne1(p[reg][j]);
    }
  }

  // ---------- X = P V (single bf16 MFMA per tile; errors enter linearly) ----------
  f32x4 xacc[4] = {z4, z4, z4, z4};
#pragma unroll
  for (int kh = 0; kh < 2; ++kh) {
    const int k0 = kh * 32 + quad * 8;
    const bf16x8 phi = *(const bf16x8*)(&s_k[0][(wave * 16 + lrow) * LSTR + k0]);
#pragma unroll
    for (int j = 0; j < 4; ++j) {
      const bf16x8 vhi = *(const bf16x8*)(&s_vt[(j * 16 + lrow) * LSTR + k0]);
      xacc[j] = __builtin_amdgcn_mfma_f32_16x16x32_bf16(phi, vhi, xacc[j], 0, 0, 0);
    }
  }

  // ---------- store x with reverse cyclic shift ----------
#pragma unroll
  for (int reg = 0; reg < 4; ++reg) {
    const int r = wave * 16 + quad * 4 + reg;
    const int gr = (win * WS + r + SHIFT) & (WTOT - 1);
    float* xrow = xout + ((size_t)batch * WTOT + gr) * WS;
#pragma unroll
    for (int j = 0; j < 4; ++j) {
      __builtin_nontemporal_store(xacc[j][reg], xrow + j * 16 + lrow);
    }
  }
}

extern "C" void kernel_launch(void* const* d_in, const int* in_sizes, int n_in,
                              void* d_out, int out_size, void* d_ws, size_t ws_size,
                              hipStream_t stream) {
  (void)in_sizes; (void)n_in; (void)out_size; (void)d_ws; (void)ws_size;
  const float* q = (const float*)d_in[0];
  const float* k = (const float*)d_in[1];
  const float* v = (const float*)d_in[2];
  const float* table = (const float*)d_in[3];
  float* xout = (float*)d_out;                               // (32, 8192, 64)
  float* attn = (float*)d_out + (size_t)32 * WTOT * WS;      // (4096, 64, 64)
  win_attn<<<dim3(4096), dim3(256), 0, stream>>>(q, k, v, table, xout, attn);
}